// Round 7
// baseline (98.343 us; speedup 1.0000x reference)
//
#include <hip/hip_runtime.h>

// LocalAggregator: semantic splatting of P=2048 3D Gaussians onto a 60x60x36
// voxel grid (N=129600 points), C=13 channels.
//
// Round 7 strategy (uniform-address VMEM eval):
//   Record-delivery paths compared across rounds:
//     R5 LDS-broadcast : 6x ds_read_b128/iter -> ~72cy/iter of per-CU LDS
//                        data-return shared by 32 waves => ~15us floor.
//     R6 scalar s_load : 192KB record stream through tiny K$, ~2 line-misses
//                        per record, shallow SQC miss-parallelism => ~20us.
//     R7 (this)        : per-lane global_load_dwordx4 at a WAVE-UNIFORM
//                        address -> HW coalesces 64 same-addr lanes into one
//                        L1 access + broadcast; deep vmcnt queue (separate
//                        from the list's lgkmcnt) -> pipelined by unroll 2
//                        + 8 waves/SIMD. g stays in a VGPR so the compiler
//                        cannot scalarize back to s_load.
//   K1 precompute: record = 24 floats [mean, log2(opac), -0.5*log2e*icov
//      (2x folded off-diags), 13 sem, pad] + int4 box array.
//   K2 agg, 2025 blocks x 256 thr (4x4x4 brick, 4 waves split the list):
//      cull -> LDS list of g | xmask<<12 | ymask<<16 | zmask<<20 (inbox test
//      in eval = 2 ops vs lane-constant sel); eval branch-free with
//      __builtin_amdgcn_exp2f (single v_exp_f32); 4-way LDS reduce + store.

constexpr int   HH      = 60;
constexpr int   WW      = 60;
constexpr int   DD      = 36;
constexpr int   P_N     = 2048;
constexpr int   C_N     = 13;
constexpr int   REC     = 24;     // floats per record (6 x float4)
constexpr int   BXD     = 15;     // bricks in x (60/4)
constexpr int   BYD     = 15;     // bricks in y
constexpr int   BZD     = 9;      // bricks in z (36/4)
constexpr int   NBRICK  = BXD * BYD * BZD;   // 2025
constexpr int   MAXL    = 256;    // list capacity (observed max ~110)
constexpr float GRID_SZ = 0.08f;

__global__ void precompute_kernel(const float* __restrict__ means,
                                  const float* __restrict__ opac,
                                  const float* __restrict__ sem,
                                  const float* __restrict__ scales,
                                  const float* __restrict__ cov,
                                  const float* __restrict__ origin,
                                  float* __restrict__ recs,
                                  int4* __restrict__ boxes) {
    int g = blockIdx.x * blockDim.x + threadIdx.x;
    if (g >= P_N) return;
    float mx = means[g * 3 + 0], my = means[g * 3 + 1], mz = means[g * 3 + 2];
    float sx = scales[g * 3 + 0], sy = scales[g * 3 + 1], sz = scales[g * 3 + 2];
    float smax = fmaxf(sx, fmaxf(sy, sz));
    int rad = (int)ceilf(smax * 3.0f / GRID_SZ);
    float ox = origin[0], oy = origin[1], oz = origin[2];
    // match reference: ((means - origin) / GRID).astype(int32)  (trunc toward 0)
    int mix = (int)((mx - ox) / GRID_SZ);
    int miy = (int)((my - oy) / GRID_SZ);
    int miz = (int)((mz - oz) / GRID_SZ);
    const float* cv = cov + g * 9;
    // packed = (xx, yy, zz, xy, yz, xz) = flat indices [0,4,8,1,5,2]
    float a = cv[0], b = cv[4], c = cv[8], d = cv[1], e = cv[5], f = cv[2];
    float det = a * (b * c - e * e) - d * (d * c - e * f) + f * (d * e - b * f);
    const float kD = -0.5f * 1.44269504088896340736f;  // -0.5 * log2(e)
    const float kO = -1.44269504088896340736f;         // folds the 2x off-diag
    float* r = recs + g * REC;
    r[0] = mx; r[1] = my; r[2] = mz;
    r[3] = __log2f(opac[g]);
    r[4] = kD * (b * c - e * e) / det;   // c_xx
    r[5] = kD * (a * c - f * f) / det;   // c_yy
    r[6] = kD * (a * b - d * d) / det;   // c_zz
    r[7] = kO * (e * f - d * c) / det;   // c_xy
    r[8] = kO * (d * f - a * e) / det;   // c_yz
    r[9] = kO * (d * e - b * f) / det;   // c_xz
#pragma unroll
    for (int cc = 0; cc < C_N; ++cc) r[10 + cc] = sem[g * C_N + cc];
    r[23] = 0.0f;
    boxes[g] = make_int4(mix, miy, miz, rad);
}

__global__ __launch_bounds__(256) void agg_kernel(const float* __restrict__ recs,
                                                  const int4* __restrict__ boxes,
                                                  float* __restrict__ out) {
    __shared__ int   s_idx[MAXL];
    __shared__ int   s_cnt;
    __shared__ float s_acc[4][64][C_N];   // 13312 B; stride 13 words -> no conflicts

    const int b = (int)blockIdx.x;
    const int bk = b % BZD; const int rem = b / BZD;
    const int bj = rem % BYD; const int bi = rem / BYD;
    const int i0 = bi * 4, j0 = bj * 4, k0 = bk * 4;

    if (threadIdx.x == 0) s_cnt = 0;
    __syncthreads();

    // --- cull: coalesced box tests; pack per-axis in-brick masks ---
    for (int g = (int)threadIdx.x; g < P_N; g += 256) {
        int4 bx = boxes[g];
        bool ov = (bx.x - bx.w <= i0 + 3) && (bx.x + bx.w >= i0)
               && (bx.y - bx.w <= j0 + 3) && (bx.y + bx.w >= j0)
               && (bx.z - bx.w <= k0 + 3) && (bx.z + bx.w >= k0);
        if (ov) {
            // per-axis masks: bit o set iff |i0+o - center| <= rad  (o in 0..3)
            int xlo = max(bx.x - bx.w - i0, 0), xhi = min(bx.x + bx.w - i0, 3);
            int ylo = max(bx.y - bx.w - j0, 0), yhi = min(bx.y + bx.w - j0, 3);
            int zlo = max(bx.z - bx.w - k0, 0), zhi = min(bx.z + bx.w - k0, 3);
            unsigned mx4 = (0xFu >> (3 - xhi)) & (0xFu << xlo);
            unsigned my4 = (0xFu >> (3 - yhi)) & (0xFu << ylo);
            unsigned mz4 = (0xFu >> (3 - zhi)) & (0xFu << zlo);
            unsigned ent = (unsigned)g | (mx4 << 12) | (my4 << 16) | (mz4 << 20);
            int t = atomicAdd(&s_cnt, 1);
            if (t < MAXL) s_idx[t] = (int)ent;
        }
    }
    __syncthreads();
    const int cnt = min(s_cnt, MAXL);

    // --- this thread's voxel ---
    const int wave = (int)threadIdx.x >> 6;
    const int lane = (int)threadIdx.x & 63;
    const int kk = lane & 3, lj = (lane >> 2) & 3, li = lane >> 4;
    const int gi = i0 + li, gj = j0 + lj, k = k0 + kk;
    // bit-exact replication of reference pts = (i + 0.5f) * GRID in fp32
    const float px = ((float)gi + 0.5f) * GRID_SZ;
    const float py = ((float)gj + 0.5f) * GRID_SZ;
    const float pz = ((float)k  + 0.5f) * GRID_SZ;
    // lane-constant selector: inbox <=> (ent & sel) == sel
    const unsigned sel = (1u << (12 + li)) | (1u << (16 + lj)) | (1u << (20 + kk));

    float acc[C_N];
#pragma unroll
    for (int cc = 0; cc < C_N; ++cc) acc[cc] = 0.0f;

    // --- eval: 4 waves split the list; records via uniform-address VMEM ---
#pragma unroll 2
    for (int i = wave; i < cnt; i += 4) {
        const unsigned ent = (unsigned)s_idx[i];      // ds_read, stays VGPR
        const int g = (int)(ent & 0xFFFu);            // VGPR -> forces VMEM path
        const float4* __restrict__ rp = (const float4*)(recs + (long)g * REC);
        const float4 r0 = rp[0];   // mean.xyz, log2(opac)
        const float4 r1 = rp[1];   // c_xx c_yy c_zz c_xy
        const float4 r2 = rp[2];   // c_yz c_xz sem0 sem1
        const float4 r3 = rp[3];   // sem2..5
        const float4 r4 = rp[4];   // sem6..9
        const float4 r5 = rp[5];   // sem10..12, pad
        const bool inbox = (ent & sel) == sel;
        const float dx = px - r0.x, dy = py - r0.y, dz = pz - r0.z;
        float e2 = r0.w;                              // log2(opac)
        e2 = fmaf(r1.x, dx * dx, e2);
        e2 = fmaf(r1.y, dy * dy, e2);
        e2 = fmaf(r1.z, dz * dz, e2);
        e2 = fmaf(r1.w, dx * dy, e2);
        e2 = fmaf(r2.x, dy * dz, e2);
        e2 = fmaf(r2.y, dx * dz, e2);
        float w = __builtin_amdgcn_exp2f(e2);         // single v_exp_f32
        w = inbox ? w : 0.0f;
        acc[0]  = fmaf(w, r2.z, acc[0]);
        acc[1]  = fmaf(w, r2.w, acc[1]);
        acc[2]  = fmaf(w, r3.x, acc[2]);
        acc[3]  = fmaf(w, r3.y, acc[3]);
        acc[4]  = fmaf(w, r3.z, acc[4]);
        acc[5]  = fmaf(w, r3.w, acc[5]);
        acc[6]  = fmaf(w, r4.x, acc[6]);
        acc[7]  = fmaf(w, r4.y, acc[7]);
        acc[8]  = fmaf(w, r4.z, acc[8]);
        acc[9]  = fmaf(w, r4.w, acc[9]);
        acc[10] = fmaf(w, r5.x, acc[10]);
        acc[11] = fmaf(w, r5.y, acc[11]);
        acc[12] = fmaf(w, r5.z, acc[12]);
    }

    // --- 4-way cross-wave reduction + store ---
#pragma unroll
    for (int cc = 0; cc < C_N; ++cc) s_acc[wave][lane][cc] = acc[cc];
    __syncthreads();

    for (int t = (int)threadIdx.x; t < 64 * C_N; t += 256) {
        const int v = t / C_N, c = t % C_N;
        const float s = s_acc[0][v][c] + s_acc[1][v][c]
                      + s_acc[2][v][c] + s_acc[3][v][c];
        const int vk = v & 3, vj = (v >> 2) & 3, vi = v >> 4;
        const long n = (long)(i0 + vi) * (WW * DD)
                     + (long)(j0 + vj) * DD + (k0 + vk);
        out[n * C_N + c] = s;
    }
}

extern "C" void kernel_launch(void* const* d_in, const int* in_sizes, int n_in,
                              void* d_out, int out_size, void* d_ws, size_t ws_size,
                              hipStream_t stream) {
    const float* means  = (const float*)d_in[1];
    const float* opac   = (const float*)d_in[2];
    const float* sem    = (const float*)d_in[3];
    const float* scales = (const float*)d_in[4];
    const float* cov    = (const float*)d_in[5];
    const float* origin = (const float*)d_in[6];
    float* out = (float*)d_out;

    char* ws = (char*)d_ws;
    float* recs  = (float*)ws;             // 2048*24*4 = 196608 B
    int4*  boxes = (int4*)(ws + 196608);   // 2048*16   =  32768 B

    precompute_kernel<<<(P_N + 255) / 256, 256, 0, stream>>>(
        means, opac, sem, scales, cov, origin, recs, boxes);
    agg_kernel<<<NBRICK, 256, 0, stream>>>(recs, boxes, out);
}

// Round 8
// 94.145 us; speedup vs baseline: 1.0446x; 1.0446x over previous
//
#include <hip/hip_runtime.h>

// LocalAggregator: semantic splatting of P=2048 3D Gaussians onto a 60x60x36
// voxel grid (N=129600 points), C=13 channels.
//
// Round 8 strategy (linear scalar-load streams):
//   Delivery history: R5 LDS-broadcast ~31us agg (per-CU LDS data-return
//   shared by 32 waves); R6 scalar s_load ~24us (dependent ds_read->s_load
//   chain, scattered 96B records = serialized K$ misses); R7 uniform VMEM
//   ~36us (worse). Fix: make the record stream LINEAR so the scalar loads
//   are independent (addr = base + i*24, no LDS dependence) -> SQC pipelines
//   them arbitrarily deep; unroll 2 keeps 2+ records in SGPR flight.
//
//   K1 precompute: record = 24 floats [mean, log2(opac), -0.5*log2e*icov
//      (2x folded off-diags), 13 sem, pad] + int4 box array.
//   K2 cull_gather (2025 blocks x 256): per-4x4x4-brick box cull; survivors'
//      records copied (coalesced float4) into a contiguous per-brick stream;
//      the pad word is overwritten with g | xmask<<12 | ymask<<16 | zmask<<20.
//   K3 agg_eval (2025 blocks x 256 = 4 waves): wave w evaluates a CONTIGUOUS
//      slice of the stream; branch-free body (inbox = 2-op mask test, single
//      v_exp_f32); 4-way cross-wave LDS reduce + store.

constexpr int   HH      = 60;
constexpr int   WW      = 60;
constexpr int   DD      = 36;
constexpr int   P_N     = 2048;
constexpr int   C_N     = 13;
constexpr int   REC     = 24;     // floats per record (6 x float4)
constexpr int   BXD     = 15;     // bricks in x (60/4)
constexpr int   BYD     = 15;     // bricks in y
constexpr int   BZD     = 9;      // bricks in z (36/4)
constexpr int   NBRICK  = BXD * BYD * BZD;   // 2025
constexpr int   MAXL    = 256;    // stream capacity/brick (observed max ~110)
constexpr float GRID_SZ = 0.08f;

__global__ void precompute_kernel(const float* __restrict__ means,
                                  const float* __restrict__ opac,
                                  const float* __restrict__ sem,
                                  const float* __restrict__ scales,
                                  const float* __restrict__ cov,
                                  const float* __restrict__ origin,
                                  float* __restrict__ recs,
                                  int4* __restrict__ boxes) {
    int g = blockIdx.x * blockDim.x + threadIdx.x;
    if (g >= P_N) return;
    float mx = means[g * 3 + 0], my = means[g * 3 + 1], mz = means[g * 3 + 2];
    float sx = scales[g * 3 + 0], sy = scales[g * 3 + 1], sz = scales[g * 3 + 2];
    float smax = fmaxf(sx, fmaxf(sy, sz));
    int rad = (int)ceilf(smax * 3.0f / GRID_SZ);
    float ox = origin[0], oy = origin[1], oz = origin[2];
    // match reference: ((means - origin) / GRID).astype(int32)  (trunc toward 0)
    int mix = (int)((mx - ox) / GRID_SZ);
    int miy = (int)((my - oy) / GRID_SZ);
    int miz = (int)((mz - oz) / GRID_SZ);
    const float* cv = cov + g * 9;
    // packed = (xx, yy, zz, xy, yz, xz) = flat indices [0,4,8,1,5,2]
    float a = cv[0], b = cv[4], c = cv[8], d = cv[1], e = cv[5], f = cv[2];
    float det = a * (b * c - e * e) - d * (d * c - e * f) + f * (d * e - b * f);
    const float kD = -0.5f * 1.44269504088896340736f;  // -0.5 * log2(e)
    const float kO = -1.44269504088896340736f;         // folds the 2x off-diag
    float* r = recs + g * REC;
    r[0] = mx; r[1] = my; r[2] = mz;
    r[3] = __log2f(opac[g]);
    r[4] = kD * (b * c - e * e) / det;   // c_xx
    r[5] = kD * (a * c - f * f) / det;   // c_yy
    r[6] = kD * (a * b - d * d) / det;   // c_zz
    r[7] = kO * (e * f - d * c) / det;   // c_xy
    r[8] = kO * (d * f - a * e) / det;   // c_yz
    r[9] = kO * (d * e - b * f) / det;   // c_xz
#pragma unroll
    for (int cc = 0; cc < C_N; ++cc) r[10 + cc] = sem[g * C_N + cc];
    r[23] = 0.0f;
    boxes[g] = make_int4(mix, miy, miz, rad);
}

__global__ __launch_bounds__(256) void cull_gather(const float* __restrict__ recs,
                                                   const int4* __restrict__ boxes,
                                                   float* __restrict__ streams,
                                                   int* __restrict__ counts) {
    __shared__ int s_idx[MAXL];
    __shared__ int s_cnt;

    const int b = (int)blockIdx.x;
    const int bk = b % BZD; const int rem = b / BZD;
    const int bj = rem % BYD; const int bi = rem / BYD;
    const int i0 = bi * 4, j0 = bj * 4, k0 = bk * 4;

    if (threadIdx.x == 0) s_cnt = 0;
    __syncthreads();

    for (int g = (int)threadIdx.x; g < P_N; g += 256) {
        int4 bx = boxes[g];
        bool ov = (bx.x - bx.w <= i0 + 3) && (bx.x + bx.w >= i0)
               && (bx.y - bx.w <= j0 + 3) && (bx.y + bx.w >= j0)
               && (bx.z - bx.w <= k0 + 3) && (bx.z + bx.w >= k0);
        if (ov) {
            // per-axis masks: bit o set iff |i0+o - center| <= rad  (o in 0..3)
            int xlo = max(bx.x - bx.w - i0, 0), xhi = min(bx.x + bx.w - i0, 3);
            int ylo = max(bx.y - bx.w - j0, 0), yhi = min(bx.y + bx.w - j0, 3);
            int zlo = max(bx.z - bx.w - k0, 0), zhi = min(bx.z + bx.w - k0, 3);
            unsigned mx4 = (0xFu >> (3 - xhi)) & (0xFu << xlo);
            unsigned my4 = (0xFu >> (3 - yhi)) & (0xFu << ylo);
            unsigned mz4 = (0xFu >> (3 - zhi)) & (0xFu << zlo);
            unsigned ent = (unsigned)g | (mx4 << 12) | (my4 << 16) | (mz4 << 20);
            int t = atomicAdd(&s_cnt, 1);
            if (t < MAXL) s_idx[t] = (int)ent;
        }
    }
    __syncthreads();
    const int cnt = min(s_cnt, MAXL);
    if (threadIdx.x == 0) counts[b] = cnt;

    // materialize the brick's survivor records contiguously (coalesced f4);
    // pad word <- packed masks+g so eval needs nothing else
    float4* dst = (float4*)(streams + (long)b * MAXL * REC);
    for (int t = (int)threadIdx.x; t < cnt * 6; t += 256) {
        const int e = t / 6, part = t % 6;
        const int ent = s_idx[e];
        const int g = ent & 0xFFF;
        float4 v = ((const float4*)(recs + (long)g * REC))[part];
        if (part == 5) v.w = __int_as_float(ent);
        dst[e * 6 + part] = v;
    }
}

__global__ __launch_bounds__(256) void agg_eval(const float* __restrict__ streams,
                                                const int* __restrict__ counts,
                                                float* __restrict__ out) {
    __shared__ float s_acc[4][64][C_N];   // 13312 B; stride 13 words -> no conflicts

    const int b = (int)blockIdx.x;
    const int bk = b % BZD; const int rem = b / BZD;
    const int bj = rem % BYD; const int bi = rem / BYD;
    const int i0 = bi * 4, j0 = bj * 4, k0 = bk * 4;

    const int wave = (int)threadIdx.x >> 6;
    const int lane = (int)threadIdx.x & 63;
    const int kk = lane & 3, lj = (lane >> 2) & 3, li = lane >> 4;
    const int gi = i0 + li, gj = j0 + lj, k = k0 + kk;
    // bit-exact replication of reference pts = (i + 0.5f) * GRID in fp32
    const float px = ((float)gi + 0.5f) * GRID_SZ;
    const float py = ((float)gj + 0.5f) * GRID_SZ;
    const float pz = ((float)k  + 0.5f) * GRID_SZ;
    // lane-constant selector: inbox <=> (ent & sel) == sel
    const unsigned sel = (1u << (12 + li)) | (1u << (16 + lj)) | (1u << (20 + kk));

    const int cnt = counts[b];
    // contiguous per-wave slice; bounds made explicitly wave-scalar
    const int q0 = __builtin_amdgcn_readfirstlane((cnt * wave) >> 2);
    const int q1 = __builtin_amdgcn_readfirstlane((cnt * (wave + 1)) >> 2);
    const float* __restrict__ base = streams + (long)b * MAXL * REC;

    float acc[C_N];
#pragma unroll
    for (int cc = 0; cc < C_N; ++cc) acc[cc] = 0.0f;

    // linear, index-computed scalar loads -> independent, deeply prefetchable
#pragma unroll 2
    for (int i = q0; i < q1; ++i) {
        const float* __restrict__ r = base + i * REC;   // uniform -> s_load
        const unsigned ent = (unsigned)__float_as_int(r[23]);
        const bool inbox = (ent & sel) == sel;
        const float dx = px - r[0], dy = py - r[1], dz = pz - r[2];
        float e2 = r[3];                       // log2(opac)
        e2 = fmaf(r[4], dx * dx, e2);
        e2 = fmaf(r[5], dy * dy, e2);
        e2 = fmaf(r[6], dz * dz, e2);
        e2 = fmaf(r[7], dx * dy, e2);
        e2 = fmaf(r[8], dy * dz, e2);
        e2 = fmaf(r[9], dx * dz, e2);
        float w = __builtin_amdgcn_exp2f(e2);  // single v_exp_f32
        w = inbox ? w : 0.0f;
#pragma unroll
        for (int cc = 0; cc < C_N; ++cc)
            acc[cc] = fmaf(w, r[10 + cc], acc[cc]);
    }

    // --- 4-way cross-wave reduction + store ---
#pragma unroll
    for (int cc = 0; cc < C_N; ++cc) s_acc[wave][lane][cc] = acc[cc];
    __syncthreads();

    for (int t = (int)threadIdx.x; t < 64 * C_N; t += 256) {
        const int v = t / C_N, c = t % C_N;
        const float s = s_acc[0][v][c] + s_acc[1][v][c]
                      + s_acc[2][v][c] + s_acc[3][v][c];
        const int vk = v & 3, vj = (v >> 2) & 3, vi = v >> 4;
        const long n = (long)(i0 + vi) * (WW * DD)
                     + (long)(j0 + vj) * DD + (k0 + vk);
        out[n * C_N + c] = s;
    }
}

extern "C" void kernel_launch(void* const* d_in, const int* in_sizes, int n_in,
                              void* d_out, int out_size, void* d_ws, size_t ws_size,
                              hipStream_t stream) {
    const float* means  = (const float*)d_in[1];
    const float* opac   = (const float*)d_in[2];
    const float* sem    = (const float*)d_in[3];
    const float* scales = (const float*)d_in[4];
    const float* cov    = (const float*)d_in[5];
    const float* origin = (const float*)d_in[6];
    float* out = (float*)d_out;

    char* ws = (char*)d_ws;
    float* recs    = (float*)ws;                    // 2048*24*4 = 196608 B
    int4*  boxes   = (int4*)(ws + 196608);          // 2048*16   =  32768 B
    int*   counts  = (int*)(ws + 196608 + 32768);   // 2025*4, pad to 8192
    float* streams = (float*)(ws + 196608 + 32768 + 8192);  // 2025*256*96 ~ 50 MB

    precompute_kernel<<<(P_N + 255) / 256, 256, 0, stream>>>(
        means, opac, sem, scales, cov, origin, recs, boxes);
    cull_gather<<<NBRICK, 256, 0, stream>>>(recs, boxes, streams, counts);
    agg_eval<<<NBRICK, 256, 0, stream>>>(streams, counts, out);
}

// Round 9
// 87.929 us; speedup vs baseline: 1.1184x; 1.0707x over previous
//
#include <hip/hip_runtime.h>

// LocalAggregator: semantic splatting of P=2048 3D Gaussians onto a 60x60x36
// voxel grid (N=129600 points), C=13 channels.
//
// Round 9 strategy (single fused kernel, zero workspace):
//   Fixed harness overhead is ~60us (41us 256MiB ws poison-fill + out poison
//   + input restore + per-dispatch gaps) -> every extra launch and every ws
//   round-trip is real cost. Delivery-path models from R5-R8:
//     uniform VMEM  ~96 clk/iter (no same-addr collapse, 6KB/iter @ 64B/clk)
//     scalar s_load ~85 clk/iter (coarse out-of-order SMEM waits)
//     uniform LDS   <=48 clk/iter (and the records never leave the CU)
//   So: ONE kernel, 2025 blocks x 256 thr (4x4x4 brick, 4 waves split list):
//     a) cull: recompute rad/m_int from raw means/scales (48KB, L1-resident;
//        ~25 VALU x 8 iters/thread) -> LDS-compact survivors as
//        g | xmask<<12 | ymask<<16 | zmask<<20 (eval inbox = 2-op mask test).
//     b) record-build: thread e computes survivor e's 24-float record
//        (mean, log2(opac), -0.5*log2e*icov with 2x folded off-diags, 13 sem,
//        packed ent) straight into LDS — one parallel scattered-load event.
//     c) eval: 4 waves split the list; 6x uniform ds_read_b128/iter,
//        branch-free body, single v_exp_f32.
//     d) 4-way cross-wave reduce (s_acc overlaid on record LDS) + store.
//   LDS ~19.2KB -> 8 blocks/CU resident -> single scheduling round, no tail.

constexpr int   HH      = 60;
constexpr int   WW      = 60;
constexpr int   DD      = 36;
constexpr int   P_N     = 2048;
constexpr int   C_N     = 13;
constexpr int   BXD     = 15;     // bricks in x (60/4)
constexpr int   BYD     = 15;     // bricks in y
constexpr int   BZD     = 9;      // bricks in z (36/4)
constexpr int   NBRICK  = BXD * BYD * BZD;   // 2025
constexpr int   CAP     = 192;    // survivor capacity (observed max ~110-130)
constexpr float GRID_SZ = 0.08f;

__global__ __launch_bounds__(256) void agg_fused(const float* __restrict__ means,
                                                 const float* __restrict__ opac,
                                                 const float* __restrict__ sem,
                                                 const float* __restrict__ scales,
                                                 const float* __restrict__ cov,
                                                 const float* __restrict__ origin,
                                                 float* __restrict__ out) {
    __shared__ int    s_idx[CAP];
    __shared__ int    s_cnt;
    __shared__ float4 s_mem[CAP * 6];          // records [CAP][6xfloat4] = 18KB
    float (*s_acc)[64][C_N] = (float (*)[64][C_N])s_mem;   // overlay for reduce

    const int b = (int)blockIdx.x;
    const int bk = b % BZD; const int rem = b / BZD;
    const int bj = rem % BYD; const int bi = rem / BYD;
    const int i0 = bi * 4, j0 = bj * 4, k0 = bk * 4;

    const float ox = origin[0], oy = origin[1], oz = origin[2];

    if (threadIdx.x == 0) s_cnt = 0;
    __syncthreads();

    // --- a) cull: recompute box from raw means/scales (L1-resident 48KB) ---
    for (int g = (int)threadIdx.x; g < P_N; g += 256) {
        const float mx = means[g * 3 + 0], my = means[g * 3 + 1], mz = means[g * 3 + 2];
        const float sx = scales[g * 3 + 0], sy = scales[g * 3 + 1], sz = scales[g * 3 + 2];
        const float smax = fmaxf(sx, fmaxf(sy, sz));
        // match reference: ceil(smax*3.0/GRID), ((means-origin)/GRID) trunc
        const int rad = (int)ceilf(smax * 3.0f / GRID_SZ);
        const int mix = (int)((mx - ox) / GRID_SZ);
        const int miy = (int)((my - oy) / GRID_SZ);
        const int miz = (int)((mz - oz) / GRID_SZ);
        const bool ov = (mix - rad <= i0 + 3) && (mix + rad >= i0)
                     && (miy - rad <= j0 + 3) && (miy + rad >= j0)
                     && (miz - rad <= k0 + 3) && (miz + rad >= k0);
        if (ov) {
            // per-axis masks: bit o set iff |i0+o - center| <= rad (o in 0..3)
            int xlo = max(mix - rad - i0, 0), xhi = min(mix + rad - i0, 3);
            int ylo = max(miy - rad - j0, 0), yhi = min(miy + rad - j0, 3);
            int zlo = max(miz - rad - k0, 0), zhi = min(miz + rad - k0, 3);
            unsigned mx4 = (0xFu >> (3 - xhi)) & (0xFu << xlo);
            unsigned my4 = (0xFu >> (3 - yhi)) & (0xFu << ylo);
            unsigned mz4 = (0xFu >> (3 - zhi)) & (0xFu << zlo);
            unsigned ent = (unsigned)g | (mx4 << 12) | (my4 << 16) | (mz4 << 20);
            int t = atomicAdd(&s_cnt, 1);
            if (t < CAP) s_idx[t] = (int)ent;
        }
    }
    __syncthreads();
    const int cnt = min(s_cnt, CAP);

    // --- b) build survivor records in LDS (thread e -> survivor e) ---
    for (int e = (int)threadIdx.x; e < cnt; e += 256) {
        const int ent = s_idx[e];
        const int g = ent & 0xFFF;
        const float* cv = cov + g * 9;
        // packed = (xx, yy, zz, xy, yz, xz) = flat indices [0,4,8,1,5,2]
        const float a = cv[0], bb = cv[4], c = cv[8], d = cv[1], e5 = cv[5], f = cv[2];
        const float det = a * (bb * c - e5 * e5) - d * (d * c - e5 * f)
                        + f * (d * e5 - bb * f);
        const float kD = -0.5f * 1.44269504088896340736f;  // -0.5 * log2(e)
        const float kO = -1.44269504088896340736f;         // folds 2x off-diag
        float4 r0, r1, r2, r3, r4, r5;
        r0.x = means[g * 3 + 0]; r0.y = means[g * 3 + 1]; r0.z = means[g * 3 + 2];
        r0.w = __log2f(opac[g]);
        r1.x = kD * (bb * c - e5 * e5) / det;   // c_xx
        r1.y = kD * (a * c - f * f) / det;      // c_yy
        r1.z = kD * (a * bb - d * d) / det;     // c_zz
        r1.w = kO * (e5 * f - d * c) / det;     // c_xy
        r2.x = kO * (d * f - a * e5) / det;     // c_yz
        r2.y = kO * (d * e5 - bb * f) / det;    // c_xz
        const float* sm = sem + g * C_N;
        r2.z = sm[0];  r2.w = sm[1];
        r3.x = sm[2];  r3.y = sm[3];  r3.z = sm[4];  r3.w = sm[5];
        r4.x = sm[6];  r4.y = sm[7];  r4.z = sm[8];  r4.w = sm[9];
        r5.x = sm[10]; r5.y = sm[11]; r5.z = sm[12];
        r5.w = __int_as_float(ent);
        float4* dst = &s_mem[e * 6];
        dst[0] = r0; dst[1] = r1; dst[2] = r2; dst[3] = r3; dst[4] = r4; dst[5] = r5;
    }
    __syncthreads();

    // --- c) eval: this thread's voxel; 4 waves split the list ---
    const int wave = (int)threadIdx.x >> 6;
    const int lane = (int)threadIdx.x & 63;
    const int kk = lane & 3, lj = (lane >> 2) & 3, li = lane >> 4;
    const int gi = i0 + li, gj = j0 + lj, k = k0 + kk;
    // bit-exact replication of reference pts = (i + 0.5f) * GRID in fp32
    const float px = ((float)gi + 0.5f) * GRID_SZ;
    const float py = ((float)gj + 0.5f) * GRID_SZ;
    const float pz = ((float)k  + 0.5f) * GRID_SZ;
    // lane-constant selector: inbox <=> (ent & sel) == sel
    const unsigned sel = (1u << (12 + li)) | (1u << (16 + lj)) | (1u << (20 + kk));

    float acc[C_N];
#pragma unroll
    for (int cc = 0; cc < C_N; ++cc) acc[cc] = 0.0f;

#pragma unroll 2
    for (int i = wave; i < cnt; i += 4) {
        const float4 r0 = s_mem[i * 6 + 0];   // mean.xyz, log2(opac)
        const float4 r1 = s_mem[i * 6 + 1];   // c_xx c_yy c_zz c_xy
        const float4 r2 = s_mem[i * 6 + 2];   // c_yz c_xz sem0 sem1
        const float4 r3 = s_mem[i * 6 + 3];   // sem2..5
        const float4 r4 = s_mem[i * 6 + 4];   // sem6..9
        const float4 r5 = s_mem[i * 6 + 5];   // sem10..12, packed ent
        const unsigned ent = (unsigned)__float_as_int(r5.w);
        const bool inbox = (ent & sel) == sel;
        const float dx = px - r0.x, dy = py - r0.y, dz = pz - r0.z;
        float e2 = r0.w;                      // log2(opac)
        e2 = fmaf(r1.x, dx * dx, e2);
        e2 = fmaf(r1.y, dy * dy, e2);
        e2 = fmaf(r1.z, dz * dz, e2);
        e2 = fmaf(r1.w, dx * dy, e2);
        e2 = fmaf(r2.x, dy * dz, e2);
        e2 = fmaf(r2.y, dx * dz, e2);
        float w = __builtin_amdgcn_exp2f(e2); // single v_exp_f32
        w = inbox ? w : 0.0f;
        acc[0]  = fmaf(w, r2.z, acc[0]);
        acc[1]  = fmaf(w, r2.w, acc[1]);
        acc[2]  = fmaf(w, r3.x, acc[2]);
        acc[3]  = fmaf(w, r3.y, acc[3]);
        acc[4]  = fmaf(w, r3.z, acc[4]);
        acc[5]  = fmaf(w, r3.w, acc[5]);
        acc[6]  = fmaf(w, r4.x, acc[6]);
        acc[7]  = fmaf(w, r4.y, acc[7]);
        acc[8]  = fmaf(w, r4.z, acc[8]);
        acc[9]  = fmaf(w, r4.w, acc[9]);
        acc[10] = fmaf(w, r5.x, acc[10]);
        acc[11] = fmaf(w, r5.y, acc[11]);
        acc[12] = fmaf(w, r5.z, acc[12]);
    }

    // --- d) 4-way cross-wave reduction (overlaid on record LDS) + store ---
    __syncthreads();   // all waves done reading records before overlay write
#pragma unroll
    for (int cc = 0; cc < C_N; ++cc) (*(&s_acc[wave]))[lane][cc] = acc[cc];
    __syncthreads();

    for (int t = (int)threadIdx.x; t < 64 * C_N; t += 256) {
        const int v = t / C_N, c = t % C_N;
        const float s = s_acc[0][v][c] + s_acc[1][v][c]
                      + s_acc[2][v][c] + s_acc[3][v][c];
        const int vk = v & 3, vj = (v >> 2) & 3, vi = v >> 4;
        const long n = (long)(i0 + vi) * (WW * DD)
                     + (long)(j0 + vj) * DD + (k0 + vk);
        out[n * C_N + c] = s;
    }
}

extern "C" void kernel_launch(void* const* d_in, const int* in_sizes, int n_in,
                              void* d_out, int out_size, void* d_ws, size_t ws_size,
                              hipStream_t stream) {
    const float* means  = (const float*)d_in[1];
    const float* opac   = (const float*)d_in[2];
    const float* sem    = (const float*)d_in[3];
    const float* scales = (const float*)d_in[4];
    const float* cov    = (const float*)d_in[5];
    const float* origin = (const float*)d_in[6];
    float* out = (float*)d_out;

    agg_fused<<<NBRICK, 256, 0, stream>>>(means, opac, sem, scales, cov,
                                          origin, out);
}

// Round 10
// 87.208 us; speedup vs baseline: 1.1277x; 1.0083x over previous
//
#include <hip/hip_runtime.h>

// LocalAggregator: semantic splatting of P=2048 3D Gaussians onto a 60x60x36
// voxel grid (N=129600 points), C=13 channels.
//
// Round 10 strategy (LDS amortization via 4x4x12 bricks):
//   Invariant found in R5-R9: per-CU LDS cycles = (bricks/CU) x cnt x 72
//   (6 uniform ds_read_b128 per record-eval) -- independent of wave split.
//   Fix: bigger brick. 4x4x12 = 192 voxels, each lane owns 3 z-voxels
//   (z, z+4, z+8) -> one record read serves 192 voxel-evals (3x R9).
//   Expected cnt/brick ~117 -> per-CU LDS ~22k cyc ~9us.
//
//   ONE kernel, 675 blocks x 256 thr (4 waves split the record list):
//     a) cull: recompute rad/m_int from raw means/scales; survivors compacted
//        to LDS as ent = g(11b) | xmask4<<11 | ymask4<<15 | zmask12<<19
//        (per-axis in-brick voxel masks -> eval inbox = 2-op mask test).
//     b) record-build in LDS: thread e computes survivor e's 24-float record
//        [mean, log2(opac), -0.5*log2e*icov (2x folded off-diags), 13 sem,
//        packed ent] -- one parallel scattered-load event.
//     c) eval: per record 6 uniform ds_read_b128; shared xy terms hoisted;
//        3 z-voxels per lane (dz-dependent: 3 mul + 3 fma + exp + 13 fma).
//     d) reduce: 3 passes through overlaid [4][64][13] buffer + store.

constexpr int   HH      = 60;
constexpr int   WW      = 60;
constexpr int   DD      = 36;
constexpr int   P_N     = 2048;
constexpr int   C_N     = 13;
constexpr int   BXD     = 15;     // bricks in x (60/4)
constexpr int   BYD     = 15;     // bricks in y
constexpr int   BZD     = 3;      // bricks in z (36/12)
constexpr int   ZCH     = 12;     // z-extent per brick
constexpr int   NBRICK  = BXD * BYD * BZD;   // 675
constexpr int   CAP     = 256;    // survivor capacity (expected ~117, max ~160)
constexpr float GRID_SZ = 0.08f;

__global__ __launch_bounds__(256) void agg_fused(const float* __restrict__ means,
                                                 const float* __restrict__ opac,
                                                 const float* __restrict__ sem,
                                                 const float* __restrict__ scales,
                                                 const float* __restrict__ cov,
                                                 const float* __restrict__ origin,
                                                 float* __restrict__ out) {
    __shared__ int    s_idx[CAP];
    __shared__ int    s_cnt;
    __shared__ float4 s_mem[CAP * 6];          // records 24.6KB; reduce overlay
    float (*s_acc)[64][C_N] = (float (*)[64][C_N])s_mem;   // 13.3KB overlay

    const int b = (int)blockIdx.x;
    const int bz = b % BZD;
    const int txy = b / BZD;
    const int bj = txy % BYD;
    const int bi = txy / BYD;
    const int i0 = bi * 4, j0 = bj * 4, k0 = bz * ZCH;

    const float ox = origin[0], oy = origin[1], oz = origin[2];

    if (threadIdx.x == 0) s_cnt = 0;
    __syncthreads();

    // --- a) cull: recompute box from raw means/scales (L1/L2-resident) ---
    for (int g = (int)threadIdx.x; g < P_N; g += 256) {
        const float mx = means[g * 3 + 0], my = means[g * 3 + 1], mz = means[g * 3 + 2];
        const float sx = scales[g * 3 + 0], sy = scales[g * 3 + 1], sz = scales[g * 3 + 2];
        const float smax = fmaxf(sx, fmaxf(sy, sz));
        // match reference: ceil(smax*3.0/GRID), ((means-origin)/GRID) trunc
        const int rad = (int)ceilf(smax * 3.0f / GRID_SZ);
        const int mix = (int)((mx - ox) / GRID_SZ);
        const int miy = (int)((my - oy) / GRID_SZ);
        const int miz = (int)((mz - oz) / GRID_SZ);
        const bool ov = (mix - rad <= i0 + 3)       && (mix + rad >= i0)
                     && (miy - rad <= j0 + 3)       && (miy + rad >= j0)
                     && (miz - rad <= k0 + ZCH - 1) && (miz + rad >= k0);
        if (ov) {
            // per-axis masks: bit o set iff |brick0+o - center| <= rad
            int xlo = max(mix - rad - i0, 0), xhi = min(mix + rad - i0, 3);
            int ylo = max(miy - rad - j0, 0), yhi = min(miy + rad - j0, 3);
            int zlo = max(miz - rad - k0, 0), zhi = min(miz + rad - k0, ZCH - 1);
            unsigned mx4  = (0xFu >> (3 - xhi)) & (0xFu << xlo);
            unsigned my4  = (0xFu >> (3 - yhi)) & (0xFu << ylo);
            unsigned mz12 = (0xFFFu >> (ZCH - 1 - zhi)) & (0xFFFu << zlo);
            unsigned ent = (unsigned)g | (mx4 << 11) | (my4 << 15) | (mz12 << 19);
            int t = atomicAdd(&s_cnt, 1);
            if (t < CAP) s_idx[t] = (int)ent;
        }
    }
    __syncthreads();
    const int cnt = min(s_cnt, CAP);

    // --- b) build survivor records in LDS (thread e -> survivor e) ---
    for (int e = (int)threadIdx.x; e < cnt; e += 256) {
        const int ent = s_idx[e];
        const int g = ent & 0x7FF;
        const float* cv = cov + g * 9;
        // packed = (xx, yy, zz, xy, yz, xz) = flat indices [0,4,8,1,5,2]
        const float a = cv[0], bb = cv[4], c = cv[8], d = cv[1], e5 = cv[5], f = cv[2];
        const float det = a * (bb * c - e5 * e5) - d * (d * c - e5 * f)
                        + f * (d * e5 - bb * f);
        const float kD = -0.5f * 1.44269504088896340736f;  // -0.5 * log2(e)
        const float kO = -1.44269504088896340736f;         // folds 2x off-diag
        float4 r0, r1, r2, r3, r4, r5;
        r0.x = means[g * 3 + 0]; r0.y = means[g * 3 + 1]; r0.z = means[g * 3 + 2];
        r0.w = __log2f(opac[g]);
        r1.x = kD * (bb * c - e5 * e5) / det;   // c_xx
        r1.y = kD * (a * c - f * f) / det;      // c_yy
        r1.z = kD * (a * bb - d * d) / det;     // c_zz
        r1.w = kO * (e5 * f - d * c) / det;     // c_xy
        r2.x = kO * (d * f - a * e5) / det;     // c_yz
        r2.y = kO * (d * e5 - bb * f) / det;    // c_xz
        const float* sm = sem + g * C_N;
        r2.z = sm[0];  r2.w = sm[1];
        r3.x = sm[2];  r3.y = sm[3];  r3.z = sm[4];  r3.w = sm[5];
        r4.x = sm[6];  r4.y = sm[7];  r4.z = sm[8];  r4.w = sm[9];
        r5.x = sm[10]; r5.y = sm[11]; r5.z = sm[12];
        r5.w = __int_as_float(ent);
        float4* dst = &s_mem[e * 6];
        dst[0] = r0; dst[1] = r1; dst[2] = r2; dst[3] = r3; dst[4] = r4; dst[5] = r5;
    }
    __syncthreads();

    // --- c) eval: lane owns 3 z-voxels; 4 waves split the list ---
    const int wave = (int)threadIdx.x >> 6;
    const int lane = (int)threadIdx.x & 63;
    const int kk = lane & 3, lj = (lane >> 2) & 3, li = lane >> 4;
    const int gi = i0 + li, gj = j0 + lj;
    // bit-exact replication of reference pts = (i + 0.5f) * GRID in fp32
    const float px = ((float)gi + 0.5f) * GRID_SZ;
    const float py = ((float)gj + 0.5f) * GRID_SZ;
    float    pzv[3];
    unsigned selv[3];
#pragma unroll
    for (int p = 0; p < 3; ++p) {
        pzv[p]  = ((float)(k0 + kk + 4 * p) + 0.5f) * GRID_SZ;
        selv[p] = (1u << (11 + li)) | (1u << (15 + lj)) | (1u << (19 + kk + 4 * p));
    }

    float acc[3][C_N];
#pragma unroll
    for (int p = 0; p < 3; ++p)
#pragma unroll
        for (int cc = 0; cc < C_N; ++cc) acc[p][cc] = 0.0f;

#pragma unroll 2
    for (int i = wave; i < cnt; i += 4) {
        const float4 r0 = s_mem[i * 6 + 0];   // mean.xyz, log2(opac)
        const float4 r1 = s_mem[i * 6 + 1];   // c_xx c_yy c_zz c_xy
        const float4 r2 = s_mem[i * 6 + 2];   // c_yz c_xz sem0 sem1
        const float4 r3 = s_mem[i * 6 + 3];   // sem2..5
        const float4 r4 = s_mem[i * 6 + 4];   // sem6..9
        const float4 r5 = s_mem[i * 6 + 5];   // sem10..12, packed ent
        const unsigned ent = (unsigned)__float_as_int(r5.w);
        const float dx = px - r0.x, dy = py - r0.y;
        // shared xy part of the base-2 exponent
        float base2 = r0.w;
        base2 = fmaf(r1.x, dx * dx, base2);
        base2 = fmaf(r1.y, dy * dy, base2);
        base2 = fmaf(r1.w, dx * dy, base2);
        float w[3];
#pragma unroll
        for (int p = 0; p < 3; ++p) {
            const float dz = pzv[p] - r0.z;
            float e2 = base2;
            e2 = fmaf(r1.z, dz * dz, e2);
            e2 = fmaf(r2.x, dy * dz, e2);
            e2 = fmaf(r2.y, dx * dz, e2);
            const float ww = __builtin_amdgcn_exp2f(e2);
            w[p] = ((ent & selv[p]) == selv[p]) ? ww : 0.0f;
        }
#pragma unroll
        for (int p = 0; p < 3; ++p) {
            acc[p][0]  = fmaf(w[p], r2.z, acc[p][0]);
            acc[p][1]  = fmaf(w[p], r2.w, acc[p][1]);
            acc[p][2]  = fmaf(w[p], r3.x, acc[p][2]);
            acc[p][3]  = fmaf(w[p], r3.y, acc[p][3]);
            acc[p][4]  = fmaf(w[p], r3.z, acc[p][4]);
            acc[p][5]  = fmaf(w[p], r3.w, acc[p][5]);
            acc[p][6]  = fmaf(w[p], r4.x, acc[p][6]);
            acc[p][7]  = fmaf(w[p], r4.y, acc[p][7]);
            acc[p][8]  = fmaf(w[p], r4.z, acc[p][8]);
            acc[p][9]  = fmaf(w[p], r4.w, acc[p][9]);
            acc[p][10] = fmaf(w[p], r5.x, acc[p][10]);
            acc[p][11] = fmaf(w[p], r5.y, acc[p][11]);
            acc[p][12] = fmaf(w[p], r5.z, acc[p][12]);
        }
    }

    // --- d) 3-pass 4-way cross-wave reduction (overlay on records) + store ---
#pragma unroll
    for (int p = 0; p < 3; ++p) {
        __syncthreads();   // records (p=0) / previous pass done before overlay
#pragma unroll
        for (int cc = 0; cc < C_N; ++cc) s_acc[wave][lane][cc] = acc[p][cc];
        __syncthreads();
        for (int t = (int)threadIdx.x; t < 64 * C_N; t += 256) {
            const int v = t / C_N, c = t % C_N;
            const float s = s_acc[0][v][c] + s_acc[1][v][c]
                          + s_acc[2][v][c] + s_acc[3][v][c];
            const int vk = v & 3, vj = (v >> 2) & 3, vi = v >> 4;
            const long n = (long)(i0 + vi) * (WW * DD)
                         + (long)(j0 + vj) * DD + (k0 + vk + 4 * p);
            out[n * C_N + c] = s;
        }
    }
}

extern "C" void kernel_launch(void* const* d_in, const int* in_sizes, int n_in,
                              void* d_out, int out_size, void* d_ws, size_t ws_size,
                              hipStream_t stream) {
    const float* means  = (const float*)d_in[1];
    const float* opac   = (const float*)d_in[2];
    const float* sem    = (const float*)d_in[3];
    const float* scales = (const float*)d_in[4];
    const float* cov    = (const float*)d_in[5];
    const float* origin = (const float*)d_in[6];
    float* out = (float*)d_out;

    agg_fused<<<NBRICK, 256, 0, stream>>>(means, opac, sem, scales, cov,
                                          origin, out);
}